// Round 1
// baseline (54.457 us; speedup 1.0000x reference)
//
#include <hip/hip_runtime.h>
#include <math.h>

// Gaussian splat rasterizer, H=W=128, N=1024.
// ws layout (floats): [0,1024) depths | [1024,13312) params unsorted | [13312,25600) params sorted
// params record (12 floats): mx, my, ias, ibs, ids, r, g, b, opac, depth, pad, pad
//   where mahal-exponent arg = ias*dx^2 + ibs*dx*dy + ids*dy^2 and weight = exp2(arg)*opac.

#define NG 1024
#define WID 128
#define HEI 128
#define P_STRIDE 12
#define CHUNK 128                      // gaussians per lane
#define NCH 8                          // lanes per pixel
#define CH_FLOATS (CHUNK * P_STRIDE)   // 1536
#define CH_STRIDE (CH_FLOATS + 4)      // 1540 -> chunk bases 4 banks apart

__global__ __launch_bounds__(256) void project_k(
    const float* __restrict__ pos, const float* __restrict__ scl,
    const float* __restrict__ rot, const float* __restrict__ col,
    const float* __restrict__ opa, const float* __restrict__ Km,
    float* __restrict__ depths, float* __restrict__ params)
{
    int g = blockIdx.x * blockDim.x + threadIdx.x;
    if (g >= NG) return;

    float X = pos[g*3+0], Y = pos[g*3+1], Z = pos[g*3+2];
    float sx = scl[g*3+0], sy = scl[g*3+1], sz = scl[g*3+2];
    float qw = rot[g*4+0], qx = rot[g*4+1], qy = rot[g*4+2], qz = rot[g*4+3];

    float qn = 1.0f / sqrtf(qw*qw + qx*qx + qy*qy + qz*qz);
    qw *= qn; qx *= qn; qy *= qn; qz *= qn;

    float r00 = 1.f - 2.f*(qy*qy + qz*qz), r01 = 2.f*(qx*qy - qw*qz), r02 = 2.f*(qx*qz + qw*qy);
    float r10 = 2.f*(qx*qy + qw*qz), r11 = 1.f - 2.f*(qx*qx + qz*qz), r12 = 2.f*(qy*qz - qw*qx);
    float r20 = 2.f*(qx*qz - qw*qy), r21 = 2.f*(qy*qz + qw*qx), r22 = 1.f - 2.f*(qx*qx + qy*qy);

    // RS = R * diag(s)
    float m00 = r00*sx, m01 = r01*sy, m02 = r02*sz;
    float m10 = r10*sx, m11 = r11*sy, m12 = r12*sz;
    float m20 = r20*sx, m21 = r21*sy, m22 = r22*sz;

    // cov3d = (RS)(RS)^T  (symmetric)
    float c00 = m00*m00 + m01*m01 + m02*m02;
    float c01 = m00*m10 + m01*m11 + m02*m12;
    float c02 = m00*m20 + m01*m21 + m02*m22;
    float c11 = m10*m10 + m11*m11 + m12*m12;
    float c12 = m10*m20 + m11*m21 + m12*m22;
    float c22 = m20*m20 + m21*m21 + m22*m22;

    float fx = Km[0], fy = Km[4], cx = Km[2], cy = Km[5];
    float zinv = 1.0f / (Z + 1e-6f);
    float mx = fx * X * zinv + cx;
    float my = fy * Y * zinv + cy;

    // J rows: (j00, 0, j02) and (0, j11, j12)
    float j00 = fx * zinv,  j02 = -fx * X * zinv * zinv;
    float j11 = fy * zinv,  j12 = -fy * Y * zinv * zinv;

    // A = J * cov3d (2x3), then cov2d = A * J^T + 1e-4 I
    float a0 = j00*c00 + j02*c02;
    float a1 = j00*c01 + j02*c12;
    float a2 = j00*c02 + j02*c22;
    float b1 = j11*c11 + j12*c12;
    float b2 = j11*c12 + j12*c22;

    float va = a0*j00 + a2*j02 + 1e-4f;    // cov2d[0][0]
    float vb = a1*j11 + a2*j12;            // cov2d[0][1] (== [1][0] by symmetry)
    float vd = b1*j11 + b2*j12 + 1e-4f;    // cov2d[1][1]

    float det  = va*vd - vb*vb;
    float idet = 1.0f / det;

    const float kf = -0.5f * 1.44269504088896340736f;  // -0.5 * log2(e)
    float ias = kf * vd * idet;
    float ibs = -2.0f * kf * vb * idet;   // coeff of dx*dy: -0.5*log2e * (-2*vb/det)
    float ids = kf * va * idet;

    bool inb = (mx >= -50.f) && (mx <= (float)(WID + 50)) &&
               (my >= -50.f) && (my <= (float)(HEI + 50));
    float op = inb ? opa[g] : 0.f;

    depths[g] = Z;
    float4* pr = (float4*)(params + g * P_STRIDE);
    pr[0] = make_float4(mx, my, ias, ibs);
    pr[1] = make_float4(ids, col[g*3+0], col[g*3+1], col[g*3+2]);
    pr[2] = make_float4(op, Z, 0.f, 0.f);
}

// Stable descending-depth rank (matches jnp.argsort(-depths)) + scatter into sorted order.
__global__ __launch_bounds__(64) void sort_k(
    const float* __restrict__ depths, const float* __restrict__ params,
    float* __restrict__ sorted)
{
    __shared__ float sd[NG];
    int tid = threadIdx.x;
    for (int k = tid; k < NG; k += 64) sd[k] = depths[k];
    __syncthreads();

    int g = blockIdx.x * 64 + tid;
    float d = sd[g];
    int rank = 0;
    #pragma unroll 8
    for (int j = 0; j < NG; ++j) {
        float dj = sd[j];
        rank += ((dj > d) || (dj == d && j < g)) ? 1 : 0;
    }
    const float4* s = (const float4*)(params + g * P_STRIDE);
    float4* t = (float4*)(sorted + rank * P_STRIDE);
    t[0] = s[0]; t[1] = s[1]; t[2] = s[2];
}

// 8 lanes per pixel; lane p composites sorted gaussians [p*128, (p+1)*128) with local
// transmittance, then lanes combine via prefix-product of T (the alpha recurrence is
// exactly separable: 1 - alpha_acc = prod(1 - alpha)).
__global__ __launch_bounds__(256) void render_k(
    const float* __restrict__ sorted, const float* __restrict__ bg,
    float* __restrict__ out)
{
    __shared__ float lds[NCH * CH_STRIDE];   // 49280 B
    int tid = threadIdx.x;

    // Stage sorted params: chunk p of 1536 floats -> lds base p*1540 (4-bank skew per chunk).
    float4* lds4 = (float4*)lds;
    const float4* src4 = (const float4*)sorted;
    #pragma unroll
    for (int n4 = tid; n4 < NG * P_STRIDE / 4; n4 += 256) {
        int p    = n4 / (CH_FLOATS / 4);        // /384
        int rem4 = n4 - p * (CH_FLOATS / 4);
        lds4[p * (CH_STRIDE / 4) + rem4] = src4[n4];
    }
    __syncthreads();

    int gt    = blockIdx.x * 256 + tid;
    int pixel = gt >> 3;
    int p     = tid & 7;
    float fpx = (float)(pixel & (WID - 1));
    float fpy = (float)(pixel >> 7);

    const float* base = lds + p * CH_STRIDE;
    float T = 1.f, sr = 0.f, sg = 0.f, sb = 0.f, sdep = 0.f, sa = 0.f;

    #pragma unroll 4
    for (int i = 0; i < CHUNK; ++i) {
        const float* gp = base + i * P_STRIDE;
        float mx  = gp[0], my  = gp[1];
        float ias = gp[2], ibs = gp[3], ids = gp[4];
        float cr  = gp[5], cg  = gp[6], cb  = gp[7];
        float op  = gp[8], dep = gp[9];

        float dx = fpx - mx, dy = fpy - my;
        float arg = ias * (dx * dx) + ibs * (dx * dy) + ids * (dy * dy);
        float w = exp2f(arg) * op;
        float alpha = (w > 0.01f) ? w : 0.f;
        float contrib = T * alpha;
        sr   = fmaf(contrib, cr, sr);
        sg   = fmaf(contrib, cg, sg);
        sb   = fmaf(contrib, cb, sb);
        sdep = fmaf(contrib, dep, sdep);
        sa  += contrib;
        T   -= contrib;
    }

    // Inclusive prefix product of T within each 8-lane group.
    float v = T;
    #pragma unroll
    for (int d = 1; d < 8; d <<= 1) {
        float u = __shfl_up(v, d, 8);
        if ((tid & 7) >= d) v *= u;
    }
    float Tpre = __shfl_up(v, 1, 8);
    if ((tid & 7) == 0) Tpre = 1.f;

    sr *= Tpre; sg *= Tpre; sb *= Tpre; sdep *= Tpre; sa *= Tpre;

    #pragma unroll
    for (int m = 1; m < 8; m <<= 1) {
        sr   += __shfl_xor(sr, m);
        sg   += __shfl_xor(sg, m);
        sb   += __shfl_xor(sb, m);
        sdep += __shfl_xor(sdep, m);
        sa   += __shfl_xor(sa, m);
    }

    if ((tid & 7) == 0) {
        float r = fminf(fmaxf(bg[0] + sr, 0.f), 1.f);
        float g = fminf(fmaxf(bg[1] + sg, 0.f), 1.f);
        float b = fminf(fmaxf(bg[2] + sb, 0.f), 1.f);
        out[pixel * 3 + 0] = r;
        out[pixel * 3 + 1] = g;
        out[pixel * 3 + 2] = b;
        out[HEI * WID * 3 + pixel] = sdep;   // depth_map
        out[HEI * WID * 4 + pixel] = sa;     // alpha_acc
    }
}

extern "C" void kernel_launch(void* const* d_in, const int* in_sizes, int n_in,
                              void* d_out, int out_size, void* d_ws, size_t ws_size,
                              hipStream_t stream)
{
    const float* pos = (const float*)d_in[0];
    const float* scl = (const float*)d_in[1];
    const float* rot = (const float*)d_in[2];
    const float* col = (const float*)d_in[3];
    const float* opa = (const float*)d_in[4];
    const float* Km  = (const float*)d_in[5];
    const float* bg  = (const float*)d_in[6];
    float* out = (float*)d_out;

    float* ws      = (float*)d_ws;
    float* depths  = ws;                 // 1024 floats
    float* params  = ws + NG;            // 12288 floats
    float* sorted  = ws + NG + NG * P_STRIDE; // 12288 floats  (total ~100 KB)

    hipLaunchKernelGGL(project_k, dim3(4),   dim3(256), 0, stream,
                       pos, scl, rot, col, opa, Km, depths, params);
    hipLaunchKernelGGL(sort_k,    dim3(16),  dim3(64),  0, stream,
                       depths, params, sorted);
    hipLaunchKernelGGL(render_k,  dim3(512), dim3(256), 0, stream,
                       sorted, bg, out);
}

// Round 2
// 26.777 us; speedup vs baseline: 2.0337x; 2.0337x over previous
//
#include <hip/hip_runtime.h>
#include <hip/hip_fp16.h>
#include <math.h>

// Gaussian splat rasterizer, H=W=128, N=1024.
// Two kernels:
//  prep_k  : stable descending-depth rank (depth = pos[:,2]) + projection, scatters
//            packed 8-float records into ws in sorted order.
//  render_k: 8x8 pixel tile per block; 16 chunk-lanes x 64 gaussians; each lane
//            composites a 2x2 pixel quad; chunks combined by transmittance
//            prefix-product (1 - alpha_acc = prod(1 - alpha), exactly separable).
// Record (8 floats): mx, my, ias, ibs, ids, depth, half2(r,g), half2(b,op)
//   exponent arg = ias*dx^2 + ibs*dx*dy + ids*dy^2  (includes -0.5*log2e), w = exp2(arg)*op.

#define NG 1024
#define WID 128
#define HEI 128
#define REC 8
#define NCH 16
#define CHUNK 64
#define CH_FLOATS (CHUNK * REC)      // 512
#define CH_STRIDE (CH_FLOATS + 4)    // 516 -> chunk bases 4 banks apart

__global__ __launch_bounds__(256) void prep_k(
    const float* __restrict__ pos, const float* __restrict__ scl,
    const float* __restrict__ rot, const float* __restrict__ col,
    const float* __restrict__ opa, const float* __restrict__ Km,
    float* __restrict__ sorted)
{
    __shared__ __align__(16) float zsh[NG];
    int tid = threadIdx.x;
    for (int j = tid; j < NG; j += 256) zsh[j] = pos[3*j + 2];
    __syncthreads();

    int h  = tid & 3;                 // quarter of the compare domain
    int gl = tid >> 2;                // 0..63
    int g  = blockIdx.x * 64 + gl;
    float zg = zsh[g];

    const float4* z4 = (const float4*)zsh;
    int cnt = 0;
    #pragma unroll 4
    for (int jj = 0; jj < 64; ++jj) {
        float4 zv = z4[h*64 + jj];
        int jb = h*256 + jj*4;
        cnt += (zv.x > zg || (zv.x == zg && (jb+0) < g)) ? 1 : 0;
        cnt += (zv.y > zg || (zv.y == zg && (jb+1) < g)) ? 1 : 0;
        cnt += (zv.z > zg || (zv.z == zg && (jb+2) < g)) ? 1 : 0;
        cnt += (zv.w > zg || (zv.w == zg && (jb+3) < g)) ? 1 : 0;
    }
    cnt += __shfl_xor(cnt, 1);
    cnt += __shfl_xor(cnt, 2);        // full stable rank
    if (h != 0) return;

    // ---- projection for gaussian g ----
    float X = pos[g*3+0], Y = pos[g*3+1], Z = pos[g*3+2];
    float sx = scl[g*3+0], sy = scl[g*3+1], sz = scl[g*3+2];
    float qw = rot[g*4+0], qx = rot[g*4+1], qy = rot[g*4+2], qz = rot[g*4+3];

    float qn = 1.0f / sqrtf(qw*qw + qx*qx + qy*qy + qz*qz);
    qw *= qn; qx *= qn; qy *= qn; qz *= qn;

    float r00 = 1.f - 2.f*(qy*qy + qz*qz), r01 = 2.f*(qx*qy - qw*qz), r02 = 2.f*(qx*qz + qw*qy);
    float r10 = 2.f*(qx*qy + qw*qz), r11 = 1.f - 2.f*(qx*qx + qz*qz), r12 = 2.f*(qy*qz - qw*qx);
    float r20 = 2.f*(qx*qz - qw*qy), r21 = 2.f*(qy*qz + qw*qx), r22 = 1.f - 2.f*(qx*qx + qy*qy);

    float m00 = r00*sx, m01 = r01*sy, m02 = r02*sz;
    float m10 = r10*sx, m11 = r11*sy, m12 = r12*sz;
    float m20 = r20*sx, m21 = r21*sy, m22 = r22*sz;

    float c00 = m00*m00 + m01*m01 + m02*m02;
    float c01 = m00*m10 + m01*m11 + m02*m12;
    float c02 = m00*m20 + m01*m21 + m02*m22;
    float c11 = m10*m10 + m11*m11 + m12*m12;
    float c12 = m10*m20 + m11*m21 + m12*m22;
    float c22 = m20*m20 + m21*m21 + m22*m22;

    float fx = Km[0], fy = Km[4], cx = Km[2], cy = Km[5];
    float zinv = 1.0f / (Z + 1e-6f);
    float mx = fx * X * zinv + cx;
    float my = fy * Y * zinv + cy;

    float j00 = fx * zinv,  j02 = -fx * X * zinv * zinv;
    float j11 = fy * zinv,  j12 = -fy * Y * zinv * zinv;

    float a0 = j00*c00 + j02*c02;
    float a1 = j00*c01 + j02*c12;
    float a2 = j00*c02 + j02*c22;
    float b1 = j11*c11 + j12*c12;
    float b2 = j11*c12 + j12*c22;

    float va = a0*j00 + a2*j02 + 1e-4f;
    float vb = a1*j11 + a2*j12;
    float vd = b1*j11 + b2*j12 + 1e-4f;

    float det  = va*vd - vb*vb;
    float idet = 1.0f / det;

    const float kf = -0.5f * 1.44269504088896340736f;  // -0.5*log2(e)
    float ias = kf * vd * idet;
    float ibs = -2.0f * kf * vb * idet;
    float ids = kf * va * idet;

    bool inb = (mx >= -50.f) && (mx <= (float)(WID + 50)) &&
               (my >= -50.f) && (my <= (float)(HEI + 50));
    float op = inb ? opa[g] : 0.f;

    union { __half2 h2; float f; } urg, ubo;
    urg.h2 = __floats2half2_rn(col[g*3+0], col[g*3+1]);
    ubo.h2 = __floats2half2_rn(col[g*3+2], op);

    float4* dst = (float4*)(sorted + cnt * REC);
    dst[0] = make_float4(mx, my, ias, ibs);
    dst[1] = make_float4(ids, Z, urg.f, ubo.f);
}

__global__ __launch_bounds__(256) void render_k(
    const float* __restrict__ sorted, const float* __restrict__ bg,
    float* __restrict__ out)
{
    __shared__ __align__(16) float lds[NCH * CH_STRIDE];   // 33024 B
    int tid = threadIdx.x;

    float4* lds4 = (float4*)lds;
    const float4* src4 = (const float4*)sorted;
    #pragma unroll
    for (int k = 0; k < 8; ++k) {
        int n4 = k*256 + tid;
        int ch = n4 >> 7, rem = n4 & 127;
        lds4[ch * (CH_STRIDE/4) + rem] = src4[n4];
    }
    __syncthreads();

    int p = tid & 15;            // chunk lane
    int q = tid >> 4;            // quad id 0..15 within the 8x8 tile
    int bx = blockIdx.x & 15, by = blockIdx.x >> 4;
    int px = bx*8 + (q & 3)*2;
    int py = by*8 + (q >> 2)*2;
    float fpx = (float)px, fpy = (float)py;

    const float4* base = (const float4*)(lds + p * CH_STRIDE);

    float T0=1.f,T1=1.f,T2=1.f,T3=1.f;
    float sr0=0,sg0=0,sb0=0,sd0=0,sa0=0;
    float sr1=0,sg1=0,sb1=0,sd1=0,sa1=0;
    float sr2=0,sg2=0,sb2=0,sd2=0,sa2=0;
    float sr3=0,sg3=0,sb3=0,sd3=0,sa3=0;

    #pragma unroll 4
    for (int i = 0; i < CHUNK; ++i) {
        float4 f0 = base[i*2];
        float4 f1 = base[i*2+1];
        float mx = f0.x, my = f0.y, ias = f0.z, ibs = f0.w;
        float ids = f1.x, dep = f1.y;
        union { float f; __half2 h2; } urg, ubo;
        urg.f = f1.z; ubo.f = f1.w;
        float cr = __low2float(urg.h2), cg = __high2float(urg.h2);
        float cb = __low2float(ubo.h2), op = __high2float(ubo.h2);

        float dx = fpx - mx, dy = fpy - my;
        float a00 = ias*(dx*dx) + ibs*(dx*dy) + ids*(dy*dy);
        float e10 = fmaf(ias, fmaf(2.f, dx, 1.f), ibs*dy);   // arg(dx+1,dy) - arg(dx,dy)
        float e01 = fmaf(ids, fmaf(2.f, dy, 1.f), ibs*dx);   // arg(dx,dy+1) - arg(dx,dy)
        float a10 = a00 + e10;
        float a01 = a00 + e01;
        float a11 = a10 + (e01 + ibs);

#define PXSTEP(A, T_, r_, g_, b_, d_, a_)            \
        {                                            \
            float w = exp2f(A) * op;                 \
            float al = (w > 0.01f) ? w : 0.f;        \
            float c = T_ * al;                       \
            r_ = fmaf(c, cr, r_);                    \
            g_ = fmaf(c, cg, g_);                    \
            b_ = fmaf(c, cb, b_);                    \
            d_ = fmaf(c, dep, d_);                   \
            a_ += c;                                 \
            T_ -= c;                                 \
        }
        PXSTEP(a00, T0, sr0, sg0, sb0, sd0, sa0)
        PXSTEP(a10, T1, sr1, sg1, sb1, sd1, sa1)
        PXSTEP(a01, T2, sr2, sg2, sb2, sd2, sa2)
        PXSTEP(a11, T3, sr3, sg3, sb3, sd3, sa3)
#undef PXSTEP
    }

    // Exclusive prefix-product of local transmittance over the 16 chunk lanes.
#define PREFIX(T_, P_)                                           \
    float P_;                                                    \
    {                                                            \
        float v = T_;                                            \
        for (int d = 1; d < 16; d <<= 1) {                       \
            float u = __shfl_up(v, d, 16);                       \
            if (p >= d) v *= u;                                  \
        }                                                        \
        float pre = __shfl_up(v, 1, 16);                         \
        P_ = (p == 0) ? 1.f : pre;                               \
    }
    PREFIX(T0, P0) PREFIX(T1, P1) PREFIX(T2, P2) PREFIX(T3, P3)
#undef PREFIX

    sr0*=P0; sg0*=P0; sb0*=P0; sd0*=P0; sa0*=P0;
    sr1*=P1; sg1*=P1; sb1*=P1; sd1*=P1; sa1*=P1;
    sr2*=P2; sg2*=P2; sb2*=P2; sd2*=P2; sa2*=P2;
    sr3*=P3; sg3*=P3; sb3*=P3; sd3*=P3; sa3*=P3;

    #pragma unroll
    for (int m = 1; m < 16; m <<= 1) {
        sr0+=__shfl_xor(sr0,m,16); sg0+=__shfl_xor(sg0,m,16); sb0+=__shfl_xor(sb0,m,16);
        sd0+=__shfl_xor(sd0,m,16); sa0+=__shfl_xor(sa0,m,16);
        sr1+=__shfl_xor(sr1,m,16); sg1+=__shfl_xor(sg1,m,16); sb1+=__shfl_xor(sb1,m,16);
        sd1+=__shfl_xor(sd1,m,16); sa1+=__shfl_xor(sa1,m,16);
        sr2+=__shfl_xor(sr2,m,16); sg2+=__shfl_xor(sg2,m,16); sb2+=__shfl_xor(sb2,m,16);
        sd2+=__shfl_xor(sd2,m,16); sa2+=__shfl_xor(sa2,m,16);
        sr3+=__shfl_xor(sr3,m,16); sg3+=__shfl_xor(sg3,m,16); sb3+=__shfl_xor(sb3,m,16);
        sd3+=__shfl_xor(sd3,m,16); sa3+=__shfl_xor(sa3,m,16);
    }

    if (p == 0) {
        float b0 = bg[0], b1 = bg[1], b2 = bg[2];
#define OUTPX(xo, yo, r_, g_, b_, d_, a_)                                 \
        {                                                                 \
            int idx = (py + yo) * WID + (px + xo);                        \
            out[idx*3+0] = fminf(fmaxf(b0 + r_, 0.f), 1.f);               \
            out[idx*3+1] = fminf(fmaxf(b1 + g_, 0.f), 1.f);               \
            out[idx*3+2] = fminf(fmaxf(b2 + b_, 0.f), 1.f);               \
            out[HEI*WID*3 + idx] = d_;                                    \
            out[HEI*WID*4 + idx] = a_;                                    \
        }
        OUTPX(0,0, sr0,sg0,sb0,sd0,sa0)
        OUTPX(1,0, sr1,sg1,sb1,sd1,sa1)
        OUTPX(0,1, sr2,sg2,sb2,sd2,sa2)
        OUTPX(1,1, sr3,sg3,sb3,sd3,sa3)
#undef OUTPX
    }
}

extern "C" void kernel_launch(void* const* d_in, const int* in_sizes, int n_in,
                              void* d_out, int out_size, void* d_ws, size_t ws_size,
                              hipStream_t stream)
{
    const float* pos = (const float*)d_in[0];
    const float* scl = (const float*)d_in[1];
    const float* rot = (const float*)d_in[2];
    const float* col = (const float*)d_in[3];
    const float* opa = (const float*)d_in[4];
    const float* Km  = (const float*)d_in[5];
    const float* bg  = (const float*)d_in[6];
    float* out = (float*)d_out;
    float* sorted = (float*)d_ws;   // 8192 floats

    hipLaunchKernelGGL(prep_k,   dim3(16),  dim3(256), 0, stream,
                       pos, scl, rot, col, opa, Km, sorted);
    hipLaunchKernelGGL(render_k, dim3(256), dim3(256), 0, stream,
                       sorted, bg, out);
}

// Round 3
// 17.446 us; speedup vs baseline: 3.1215x; 1.5349x over previous
//
#include <hip/hip_runtime.h>
#include <hip/hip_fp16.h>
#include <math.h>

// Gaussian splat rasterizer, H=W=128, N=1024, with exact tile culling.
// prep_k  : stable descending-depth rank (depth = pos[:,2]) + projection; scatters
//           packed 8-float records AND (mx,my,R2) cull records in sorted order.
// render_k: one 8x8 tile per block (256 blocks, 256 thr). Phase A: test all 1024
//           gaussians vs tile (keep iff d^2 < R2 where R2 = 1.02*lamMax*2ln(100 op));
//           alpha==0 for culled ones, so compositing result is unchanged.
//           Phase B: stable ordered compaction via ballot+popc. Phase C: stage the
//           surviving records into LDS. Phase D: 4 lanes/pixel composite with
//           transmittance prefix-product combine (exactly separable recurrence).
// Record (8 floats): mx, my, ias, ibs, ids, depth, half2(r,g), half2(b,op)
//   exponent arg = ias*dx^2 + ibs*dx*dy + ids*dy^2 (includes -0.5*log2e), w = exp2(arg)*op.

#define NG 1024
#define WID 128
#define HEI 128
#define REC 8

__global__ __launch_bounds__(256) void prep_k(
    const float* __restrict__ pos, const float* __restrict__ scl,
    const float* __restrict__ rot, const float* __restrict__ col,
    const float* __restrict__ opa, const float* __restrict__ Km,
    float* __restrict__ rec, float4* __restrict__ cullA)
{
    __shared__ __align__(16) float zsh[NG];
    int tid = threadIdx.x;
    for (int j = tid; j < NG; j += 256) zsh[j] = pos[3*j + 2];
    __syncthreads();

    int h  = tid & 15;                // 16-way split of the 1024 compares
    int gl = tid >> 4;                // 0..15
    int g  = blockIdx.x * 16 + gl;
    float zg = zsh[g];

    const float4* z4 = (const float4*)zsh;
    int cnt = 0;
    #pragma unroll
    for (int jj = 0; jj < 16; ++jj) {
        float4 zv = z4[h*16 + jj];
        int jb = h*64 + jj*4;
        cnt += (zv.x > zg || (zv.x == zg && (jb+0) < g)) ? 1 : 0;
        cnt += (zv.y > zg || (zv.y == zg && (jb+1) < g)) ? 1 : 0;
        cnt += (zv.z > zg || (zv.z == zg && (jb+2) < g)) ? 1 : 0;
        cnt += (zv.w > zg || (zv.w == zg && (jb+3) < g)) ? 1 : 0;
    }
    cnt += __shfl_xor(cnt, 1, 16);
    cnt += __shfl_xor(cnt, 2, 16);
    cnt += __shfl_xor(cnt, 4, 16);
    cnt += __shfl_xor(cnt, 8, 16);    // full stable rank
    if (h != 0) return;

    // ---- projection for gaussian g ----
    float X = pos[g*3+0], Y = pos[g*3+1], Z = pos[g*3+2];
    float sx = scl[g*3+0], sy = scl[g*3+1], sz = scl[g*3+2];
    float qw = rot[g*4+0], qx = rot[g*4+1], qy = rot[g*4+2], qz = rot[g*4+3];

    float qn = 1.0f / sqrtf(qw*qw + qx*qx + qy*qy + qz*qz);
    qw *= qn; qx *= qn; qy *= qn; qz *= qn;

    float r00 = 1.f - 2.f*(qy*qy + qz*qz), r01 = 2.f*(qx*qy - qw*qz), r02 = 2.f*(qx*qz + qw*qy);
    float r10 = 2.f*(qx*qy + qw*qz), r11 = 1.f - 2.f*(qx*qx + qz*qz), r12 = 2.f*(qy*qz - qw*qx);
    float r20 = 2.f*(qx*qz - qw*qy), r21 = 2.f*(qy*qz + qw*qx), r22 = 1.f - 2.f*(qx*qx + qy*qy);

    float m00 = r00*sx, m01 = r01*sy, m02 = r02*sz;
    float m10 = r10*sx, m11 = r11*sy, m12 = r12*sz;
    float m20 = r20*sx, m21 = r21*sy, m22 = r22*sz;

    float c00 = m00*m00 + m01*m01 + m02*m02;
    float c01 = m00*m10 + m01*m11 + m02*m12;
    float c02 = m00*m20 + m01*m21 + m02*m22;
    float c11 = m10*m10 + m11*m11 + m12*m12;
    float c12 = m10*m20 + m11*m21 + m12*m22;
    float c22 = m20*m20 + m21*m21 + m22*m22;

    float fx = Km[0], fy = Km[4], cx = Km[2], cy = Km[5];
    float zinv = 1.0f / (Z + 1e-6f);
    float mx = fx * X * zinv + cx;
    float my = fy * Y * zinv + cy;

    float j00 = fx * zinv,  j02 = -fx * X * zinv * zinv;
    float j11 = fy * zinv,  j12 = -fy * Y * zinv * zinv;

    float a0 = j00*c00 + j02*c02;
    float a1 = j00*c01 + j02*c12;
    float a2 = j00*c02 + j02*c22;
    float b1 = j11*c11 + j12*c12;
    float b2 = j11*c12 + j12*c22;

    float va = a0*j00 + a2*j02 + 1e-4f;
    float vb = a1*j11 + a2*j12;
    float vd = b1*j11 + b2*j12 + 1e-4f;

    float det  = va*vd - vb*vb;
    float idet = 1.0f / det;

    const float kf = -0.5f * 1.44269504088896340736f;  // -0.5*log2(e)
    float ias = kf * vd * idet;
    float ibs = -2.0f * kf * vb * idet;
    float ids = kf * va * idet;

    bool inb = (mx >= -50.f) && (mx <= (float)(WID + 50)) &&
               (my >= -50.f) && (my <= (float)(HEI + 50));
    float op = inb ? opa[g] : 0.f;

    // conservative cull radius^2: w>0.01 requires mahal < 2 ln(100 op);
    // mahal >= d^2 / lamMax  =>  keep iff d^2 < lamMax * 2 ln(100 op)
    float lmax = 0.5f*(va + vd) + sqrtf(0.25f*(va - vd)*(va - vd) + vb*vb);
    float R2 = -1.0f;
    if (op > 0.01f) {
        float mthr = 2.0f * (__logf(op) + 4.6051701859880914f);  // 2 ln(100 op)
        R2 = lmax * mthr * 1.02f + 0.01f;
    }

    union { __half2 h2; float f; } urg, ubo;
    urg.h2 = __floats2half2_rn(col[g*3+0], col[g*3+1]);
    ubo.h2 = __floats2half2_rn(col[g*3+2], op);

    float4* dst = (float4*)(rec + cnt * REC);
    dst[0] = make_float4(mx, my, ias, ibs);
    dst[1] = make_float4(ids, Z, urg.f, ubo.f);
    cullA[cnt] = make_float4(mx, my, R2, 0.f);
}

__global__ __launch_bounds__(256) void render_k(
    const float* __restrict__ rec, const float4* __restrict__ cullA,
    const float* __restrict__ bg, float* __restrict__ out)
{
    __shared__ unsigned long long masks[16];
    __shared__ int counts[16];
    __shared__ int list[NG];
    __shared__ __align__(16) float recL[NG * REC];   // 32 KB

    int tid = threadIdx.x;
    int wv = tid >> 6, ln = tid & 63;
    int bx = blockIdx.x & 15, by = blockIdx.x >> 4;
    float x0 = (float)(bx*8), x1 = x0 + 7.f;
    float y0 = (float)(by*8), y1 = y0 + 7.f;

    // Phase A: tile-vs-gaussian tests, 64 sorted ids per ballot round (stable order).
    #pragma unroll
    for (int r = 0; r < 4; ++r) {
        int gr = wv*4 + r;
        int id = gr*64 + ln;
        float4 c = cullA[id];
        float ddx = fmaxf(fmaxf(x0 - c.x, c.x - x1), 0.f);
        float ddy = fmaxf(fmaxf(y0 - c.y, c.y - y1), 0.f);
        bool keep = (ddx*ddx + ddy*ddy) < c.z;
        unsigned long long m = __ballot(keep);
        if (ln == 0) { masks[gr] = m; counts[gr] = (int)__popcll(m); }
    }
    __syncthreads();

    // Phase B: stable ordered compaction.
    int len = 0;
    #pragma unroll
    for (int j = 0; j < 16; ++j) len += counts[j];

    #pragma unroll
    for (int r = 0; r < 4; ++r) {
        int gr = wv*4 + r;
        int base = 0;
        #pragma unroll
        for (int j = 0; j < 16; ++j) base += (j < gr) ? counts[j] : 0;
        unsigned long long m = masks[gr];
        if ((m >> ln) & 1ull) {
            int p = base + (int)__popcll(m & ((1ull << ln) - 1ull));
            list[p] = gr*64 + ln;
        }
    }
    __syncthreads();

    // Phase C: stage surviving records into LDS (in sorted order).
    float4* recL4 = (float4*)recL;
    const float4* rec4g = (const float4*)rec;
    for (int i = tid; i < len; i += 256) {
        int id = list[i];
        recL4[2*i]   = rec4g[2*id];
        recL4[2*i+1] = rec4g[2*id+1];
    }
    __syncthreads();

    // Phase D: composite. 4 chunk-lanes per pixel, 64 pixels.
    int p   = tid & 3;
    int pix = tid >> 2;
    int px  = bx*8 + (pix & 7);
    int py  = by*8 + (pix >> 3);
    float fpx = (float)px, fpy = (float)py;

    int L4 = (len + 3) >> 2;
    int s0 = p * L4;
    int s1 = min(len, s0 + L4);

    float T = 1.f, sr = 0.f, sg = 0.f, sb = 0.f, sd = 0.f, sa = 0.f;
    if (s0 < s1) {
        float4 f0 = recL4[2*s0], f1 = recL4[2*s0+1];
        for (int i = s0; i < s1; ++i) {
            int j = i + 1; j = (j < s1) ? j : (s1 - 1);
            float4 n0 = recL4[2*j], n1 = recL4[2*j+1];

            float mx = f0.x, my = f0.y, ias = f0.z, ibs = f0.w;
            float ids = f1.x, dep = f1.y;
            union { float f; __half2 h2; } urg, ubo;
            urg.f = f1.z; ubo.f = f1.w;
            float cr = __low2float(urg.h2), cg = __high2float(urg.h2);
            float cb = __low2float(ubo.h2), op = __high2float(ubo.h2);

            float dx = fpx - mx, dy = fpy - my;
            float arg = ias*(dx*dx) + ibs*(dx*dy) + ids*(dy*dy);
            float w = exp2f(arg) * op;
            float al = (w > 0.01f) ? w : 0.f;
            float c = T * al;
            sr = fmaf(c, cr, sr);
            sg = fmaf(c, cg, sg);
            sb = fmaf(c, cb, sb);
            sd = fmaf(c, dep, sd);
            sa += c;
            T  -= c;

            f0 = n0; f1 = n1;
        }
    }

    // Combine the 4 chunk lanes: exclusive prefix-product of T, then sum.
    float v = T;
    #pragma unroll
    for (int d = 1; d < 4; d <<= 1) {
        float u = __shfl_up(v, d, 4);
        if (p >= d) v *= u;
    }
    float pre = __shfl_up(v, 1, 4);
    float P = (p == 0) ? 1.f : pre;

    sr *= P; sg *= P; sb *= P; sd *= P; sa *= P;
    #pragma unroll
    for (int m = 1; m < 4; m <<= 1) {
        sr += __shfl_xor(sr, m, 4);
        sg += __shfl_xor(sg, m, 4);
        sb += __shfl_xor(sb, m, 4);
        sd += __shfl_xor(sd, m, 4);
        sa += __shfl_xor(sa, m, 4);
    }

    if (p == 0) {
        int idx = py * WID + px;
        out[idx*3+0] = fminf(fmaxf(bg[0] + sr, 0.f), 1.f);
        out[idx*3+1] = fminf(fmaxf(bg[1] + sg, 0.f), 1.f);
        out[idx*3+2] = fminf(fmaxf(bg[2] + sb, 0.f), 1.f);
        out[HEI*WID*3 + idx] = sd;
        out[HEI*WID*4 + idx] = sa;
    }
}

extern "C" void kernel_launch(void* const* d_in, const int* in_sizes, int n_in,
                              void* d_out, int out_size, void* d_ws, size_t ws_size,
                              hipStream_t stream)
{
    const float* pos = (const float*)d_in[0];
    const float* scl = (const float*)d_in[1];
    const float* rot = (const float*)d_in[2];
    const float* col = (const float*)d_in[3];
    const float* opa = (const float*)d_in[4];
    const float* Km  = (const float*)d_in[5];
    const float* bg  = (const float*)d_in[6];
    float* out = (float*)d_out;

    float*  rec   = (float*)d_ws;                 // 8192 floats
    float4* cullA = (float4*)((float*)d_ws + NG*REC);  // 1024 float4

    hipLaunchKernelGGL(prep_k,   dim3(64),  dim3(256), 0, stream,
                       pos, scl, rot, col, opa, Km, rec, cullA);
    hipLaunchKernelGGL(render_k, dim3(256), dim3(256), 0, stream,
                       rec, cullA, bg, out);
}

// Round 4
// 16.483 us; speedup vs baseline: 3.3038x; 1.0584x over previous
//
#include <hip/hip_runtime.h>
#include <hip/hip_fp16.h>
#include <math.h>

// Gaussian splat rasterizer, H=W=128, N=1024 — single fused kernel.
// One block per 8x8 tile (256 blocks, 256 threads). Per block:
//  Phase 0: project ALL 1024 gaussians (redundant across blocks, 4/thread) into LDS
//           records + cull records (by gaussian id).
//  Phase A: tile-vs-gaussian conservative cull (keep iff dist^2 to tile rect < R2,
//           R2 = 1.02 * lamMax * 2 ln(100 op); culled => alpha exactly 0, lossless).
//  Phase B: stable ballot+popc compaction in id order; survivor depths -> sdep.
//  Phase C: local stable rank by (depth desc, id asc) among survivors only —
//           relative order of survivors equals global sorted order restricted to them.
//  Phase D: 4 chunk-lanes per pixel composite; chunks combined by transmittance
//           prefix-product (1 - alpha_acc = prod(1 - alpha), exactly separable).
// Record A: mx, my, ias, ibs   Record B: ids, depth, half2(r,g), half2(b,op)
//   exponent arg = ias*dx^2 + ibs*dx*dy + ids*dy^2 (includes -0.5*log2e), w = exp2(arg)*op.

#define NG 1024
#define WID 128
#define HEI 128

__global__ __launch_bounds__(256) void splat_k(
    const float* __restrict__ pos, const float* __restrict__ scl,
    const float* __restrict__ rot, const float* __restrict__ col,
    const float* __restrict__ opa, const float* __restrict__ Km,
    const float* __restrict__ bg, float* __restrict__ out)
{
    __shared__ __align__(16) float4 recA[NG];       // 16 KB
    __shared__ __align__(16) float4 recB[NG];       // 16 KB
    __shared__ __align__(16) float4 cullL[NG];      // 16 KB  (mx, my, R2, -)
    __shared__ __align__(16) float sdep[NG + 4];    // 4 KB + pad
    __shared__ int list[NG];                        // 4 KB
    __shared__ int slist2[NG];                      // 4 KB
    __shared__ unsigned long long masks[16];
    __shared__ int counts[16];

    int tid = threadIdx.x;
    float fx = Km[0], fy = Km[4], cx = Km[2], cy = Km[5];

    // ---- Phase 0: projection (4 gaussians per thread) ----
    #pragma unroll
    for (int k = 0; k < 4; ++k) {
        int g = k * 256 + tid;

        float X = pos[g*3+0], Y = pos[g*3+1], Z = pos[g*3+2];
        float sx = scl[g*3+0], sy = scl[g*3+1], sz = scl[g*3+2];
        float qw = rot[g*4+0], qx = rot[g*4+1], qy = rot[g*4+2], qz = rot[g*4+3];

        float qn = 1.0f / sqrtf(qw*qw + qx*qx + qy*qy + qz*qz);
        qw *= qn; qx *= qn; qy *= qn; qz *= qn;

        float r00 = 1.f - 2.f*(qy*qy + qz*qz), r01 = 2.f*(qx*qy - qw*qz), r02 = 2.f*(qx*qz + qw*qy);
        float r10 = 2.f*(qx*qy + qw*qz), r11 = 1.f - 2.f*(qx*qx + qz*qz), r12 = 2.f*(qy*qz - qw*qx);
        float r20 = 2.f*(qx*qz - qw*qy), r21 = 2.f*(qy*qz + qw*qx), r22 = 1.f - 2.f*(qx*qx + qy*qy);

        float m00 = r00*sx, m01 = r01*sy, m02 = r02*sz;
        float m10 = r10*sx, m11 = r11*sy, m12 = r12*sz;
        float m20 = r20*sx, m21 = r21*sy, m22 = r22*sz;

        float c00 = m00*m00 + m01*m01 + m02*m02;
        float c01 = m00*m10 + m01*m11 + m02*m12;
        float c02 = m00*m20 + m01*m21 + m02*m22;
        float c11 = m10*m10 + m11*m11 + m12*m12;
        float c12 = m10*m20 + m11*m21 + m12*m22;
        float c22 = m20*m20 + m21*m21 + m22*m22;

        float zinv = 1.0f / (Z + 1e-6f);
        float mx = fx * X * zinv + cx;
        float my = fy * Y * zinv + cy;

        float j00 = fx * zinv,  j02 = -fx * X * zinv * zinv;
        float j11 = fy * zinv,  j12 = -fy * Y * zinv * zinv;

        float a0 = j00*c00 + j02*c02;
        float a1 = j00*c01 + j02*c12;
        float a2 = j00*c02 + j02*c22;
        float b1 = j11*c11 + j12*c12;
        float b2 = j11*c12 + j12*c22;

        float va = a0*j00 + a2*j02 + 1e-4f;
        float vb = a1*j11 + a2*j12;
        float vd = b1*j11 + b2*j12 + 1e-4f;

        float det  = va*vd - vb*vb;
        float idet = 1.0f / det;

        const float kf = -0.5f * 1.44269504088896340736f;  // -0.5*log2(e)
        float ias = kf * vd * idet;
        float ibs = -2.0f * kf * vb * idet;
        float ids = kf * va * idet;

        bool inb = (mx >= -50.f) && (mx <= (float)(WID + 50)) &&
                   (my >= -50.f) && (my <= (float)(HEI + 50));
        float op = inb ? opa[g] : 0.f;

        float lmax = 0.5f*(va + vd) + sqrtf(0.25f*(va - vd)*(va - vd) + vb*vb);
        float R2 = -1.0f;
        if (op > 0.01f) {
            float mthr = 2.0f * (__logf(op) + 4.6051701859880914f);  // 2 ln(100 op)
            R2 = lmax * mthr * 1.02f + 0.01f;
        }

        union { __half2 h2; float f; } urg, ubo;
        urg.h2 = __floats2half2_rn(col[g*3+0], col[g*3+1]);
        ubo.h2 = __floats2half2_rn(col[g*3+2], op);

        recA[g]  = make_float4(mx, my, ias, ibs);
        recB[g]  = make_float4(ids, Z, urg.f, ubo.f);
        cullL[g] = make_float4(mx, my, R2, 0.f);
    }
    __syncthreads();

    // ---- Phase A: cull vs this tile ----
    int wv = tid >> 6, ln = tid & 63;
    int bx = blockIdx.x & 15, by = blockIdx.x >> 4;
    float x0 = (float)(bx*8), x1 = x0 + 7.f;
    float y0 = (float)(by*8), y1 = y0 + 7.f;

    #pragma unroll
    for (int r = 0; r < 4; ++r) {
        int gr = wv*4 + r;
        float4 c = cullL[gr*64 + ln];
        float ddx = fmaxf(fmaxf(x0 - c.x, c.x - x1), 0.f);
        float ddy = fmaxf(fmaxf(y0 - c.y, c.y - y1), 0.f);
        bool keep = (ddx*ddx + ddy*ddy) < c.z;
        unsigned long long m = __ballot(keep);
        if (ln == 0) { masks[gr] = m; counts[gr] = (int)__popcll(m); }
    }
    __syncthreads();

    // ---- Phase B: stable compaction (id order) + survivor depths ----
    int len = 0;
    #pragma unroll
    for (int j = 0; j < 16; ++j) len += counts[j];

    #pragma unroll
    for (int r = 0; r < 4; ++r) {
        int gr = wv*4 + r;
        int base = 0;
        #pragma unroll
        for (int j = 0; j < 16; ++j) base += (j < gr) ? counts[j] : 0;
        unsigned long long m = masks[gr];
        if ((m >> ln) & 1ull) {
            int id = gr*64 + ln;
            int p = base + (int)__popcll(m & ((1ull << ln) - 1ull));
            list[p] = id;
            sdep[p] = recB[id].y;
        }
    }
    if (tid < 4) sdep[len + tid] = -INFINITY;   // pad for float4 rank loop
    __syncthreads();

    // ---- Phase C: local stable rank by (depth desc, id asc) ----
    const float4* sdep4 = (const float4*)sdep;
    int L4r = (len + 3) >> 2;
    for (int i = tid; i < len; i += 256) {
        float d = sdep[i];
        int rank = 0;
        for (int j4 = 0; j4 < L4r; ++j4) {
            float4 z = sdep4[j4];
            int jb = j4*4;
            rank += (z.x > d || (z.x == d && (jb+0) < i)) ? 1 : 0;
            rank += (z.y > d || (z.y == d && (jb+1) < i)) ? 1 : 0;
            rank += (z.z > d || (z.z == d && (jb+2) < i)) ? 1 : 0;
            rank += (z.w > d || (z.w == d && (jb+3) < i)) ? 1 : 0;
        }
        slist2[rank] = list[i];
    }
    __syncthreads();

    // ---- Phase D: composite (4 chunk-lanes per pixel) ----
    int p   = tid & 3;
    int pix = tid >> 2;
    int px  = bx*8 + (pix & 7);
    int py  = by*8 + (pix >> 3);
    float fpx = (float)px, fpy = (float)py;

    int L4 = (len + 3) >> 2;
    int s0 = p * L4;
    int s1 = min(len, s0 + L4);

    float T = 1.f, sr = 0.f, sg = 0.f, sb = 0.f, sd = 0.f, sa = 0.f;
    for (int i = s0; i < s1; ++i) {
        int id = slist2[i];
        float4 f0 = recA[id];
        float4 f1 = recB[id];

        float mx = f0.x, my = f0.y, ias = f0.z, ibs = f0.w;
        float ids = f1.x, dep = f1.y;
        union { float f; __half2 h2; } urg, ubo;
        urg.f = f1.z; ubo.f = f1.w;
        float cr = __low2float(urg.h2), cg = __high2float(urg.h2);
        float cb = __low2float(ubo.h2), op = __high2float(ubo.h2);

        float dx = fpx - mx, dy = fpy - my;
        float arg = ias*(dx*dx) + ibs*(dx*dy) + ids*(dy*dy);
        float w = exp2f(arg) * op;
        float al = (w > 0.01f) ? w : 0.f;
        float c = T * al;
        sr = fmaf(c, cr, sr);
        sg = fmaf(c, cg, sg);
        sb = fmaf(c, cb, sb);
        sd = fmaf(c, dep, sd);
        sa += c;
        T  -= c;
    }

    // Combine 4 chunk lanes: exclusive prefix-product of T, then sum.
    float v = T;
    #pragma unroll
    for (int d = 1; d < 4; d <<= 1) {
        float u = __shfl_up(v, d, 4);
        if (p >= d) v *= u;
    }
    float pre = __shfl_up(v, 1, 4);
    float P = (p == 0) ? 1.f : pre;

    sr *= P; sg *= P; sb *= P; sd *= P; sa *= P;
    #pragma unroll
    for (int m = 1; m < 4; m <<= 1) {
        sr += __shfl_xor(sr, m, 4);
        sg += __shfl_xor(sg, m, 4);
        sb += __shfl_xor(sb, m, 4);
        sd += __shfl_xor(sd, m, 4);
        sa += __shfl_xor(sa, m, 4);
    }

    if (p == 0) {
        int idx = py * WID + px;
        out[idx*3+0] = fminf(fmaxf(bg[0] + sr, 0.f), 1.f);
        out[idx*3+1] = fminf(fmaxf(bg[1] + sg, 0.f), 1.f);
        out[idx*3+2] = fminf(fmaxf(bg[2] + sb, 0.f), 1.f);
        out[HEI*WID*3 + idx] = sd;
        out[HEI*WID*4 + idx] = sa;
    }
}

extern "C" void kernel_launch(void* const* d_in, const int* in_sizes, int n_in,
                              void* d_out, int out_size, void* d_ws, size_t ws_size,
                              hipStream_t stream)
{
    const float* pos = (const float*)d_in[0];
    const float* scl = (const float*)d_in[1];
    const float* rot = (const float*)d_in[2];
    const float* col = (const float*)d_in[3];
    const float* opa = (const float*)d_in[4];
    const float* Km  = (const float*)d_in[5];
    const float* bg  = (const float*)d_in[6];
    float* out = (float*)d_out;

    hipLaunchKernelGGL(splat_k, dim3(256), dim3(256), 0, stream,
                       pos, scl, rot, col, opa, Km, bg, out);
}

// Round 5
// 14.157 us; speedup vs baseline: 3.8468x; 1.1644x over previous
//
#include <hip/hip_runtime.h>
#include <hip/hip_fp16.h>
#include <math.h>

// Gaussian splat rasterizer, H=W=128, N=1024 — single fused kernel, 1024-thread blocks.
// One block per 8x8 tile (256 blocks). 16 waves/block = 4 waves/SIMD for latency hiding.
//  Phase 0: project all 1024 gaussians, 1 per thread (redundant per block) -> LDS.
//  Phase A: conservative tile cull, one ballot per wave (gaussian id == tid).
//           keep iff dist^2(mean, tile rect) < R2, R2 = 1.02*lamMax*2ln(100 op);
//           culled => alpha exactly 0, lossless.
//  Phase B: stable ballot+popc compaction in id order.
//  Phase C: local stable rank by (depth desc, id asc) among survivors (one i/thread).
//  Phase D: 16 chunk-lanes per pixel; chunks combined by transmittance prefix-product
//           (1 - alpha_acc = prod(1 - alpha), exactly separable).
// Record A: mx, my, ias, ibs   Record B: ids, depth, half2(r,g), half2(b,op)
//   exponent arg = ias*dx^2 + ibs*dx*dy + ids*dy^2 (includes -0.5*log2e), w = exp2(arg)*op.

#define NG 1024
#define WID 128
#define HEI 128

__global__ __launch_bounds__(1024) void splat_k(
    const float* __restrict__ pos, const float* __restrict__ scl,
    const float* __restrict__ rot, const float* __restrict__ col,
    const float* __restrict__ opa, const float* __restrict__ Km,
    const float* __restrict__ bg, float* __restrict__ out)
{
    __shared__ __align__(16) float4 recA[NG];       // 16 KB
    __shared__ __align__(16) float4 recB[NG];       // 16 KB
    __shared__ float cullR2[NG];                    // 4 KB
    __shared__ __align__(16) float sdep[NG + 4];    // 4 KB + pad
    __shared__ int list[NG];                        // 4 KB
    __shared__ int slist2[NG];                      // 4 KB
    __shared__ unsigned long long masks[16];
    __shared__ int counts[16];

    int tid = threadIdx.x;
    int wv = tid >> 6, ln = tid & 63;
    float fx = Km[0], fy = Km[4], cx = Km[2], cy = Km[5];

    // ---- Phase 0: projection, one gaussian per thread ----
    {
        int g = tid;
        float X = pos[g*3+0], Y = pos[g*3+1], Z = pos[g*3+2];
        float sx = scl[g*3+0], sy = scl[g*3+1], sz = scl[g*3+2];
        float4 q4 = ((const float4*)rot)[g];
        float qw = q4.x, qx = q4.y, qy = q4.z, qz = q4.w;

        float qn = 1.0f / sqrtf(qw*qw + qx*qx + qy*qy + qz*qz);
        qw *= qn; qx *= qn; qy *= qn; qz *= qn;

        float r00 = 1.f - 2.f*(qy*qy + qz*qz), r01 = 2.f*(qx*qy - qw*qz), r02 = 2.f*(qx*qz + qw*qy);
        float r10 = 2.f*(qx*qy + qw*qz), r11 = 1.f - 2.f*(qx*qx + qz*qz), r12 = 2.f*(qy*qz - qw*qx);
        float r20 = 2.f*(qx*qz - qw*qy), r21 = 2.f*(qy*qz + qw*qx), r22 = 1.f - 2.f*(qx*qx + qy*qy);

        float m00 = r00*sx, m01 = r01*sy, m02 = r02*sz;
        float m10 = r10*sx, m11 = r11*sy, m12 = r12*sz;
        float m20 = r20*sx, m21 = r21*sy, m22 = r22*sz;

        float c00 = m00*m00 + m01*m01 + m02*m02;
        float c01 = m00*m10 + m01*m11 + m02*m12;
        float c02 = m00*m20 + m01*m21 + m02*m22;
        float c11 = m10*m10 + m11*m11 + m12*m12;
        float c12 = m10*m20 + m11*m21 + m12*m22;
        float c22 = m20*m20 + m21*m21 + m22*m22;

        float zinv = 1.0f / (Z + 1e-6f);
        float mx = fx * X * zinv + cx;
        float my = fy * Y * zinv + cy;

        float j00 = fx * zinv,  j02 = -fx * X * zinv * zinv;
        float j11 = fy * zinv,  j12 = -fy * Y * zinv * zinv;

        float a0 = j00*c00 + j02*c02;
        float a1 = j00*c01 + j02*c12;
        float a2 = j00*c02 + j02*c22;
        float b1 = j11*c11 + j12*c12;
        float b2 = j11*c12 + j12*c22;

        float va = a0*j00 + a2*j02 + 1e-4f;
        float vb = a1*j11 + a2*j12;
        float vd = b1*j11 + b2*j12 + 1e-4f;

        float det  = va*vd - vb*vb;
        float idet = 1.0f / det;

        const float kf = -0.5f * 1.44269504088896340736f;  // -0.5*log2(e)
        float ias = kf * vd * idet;
        float ibs = -2.0f * kf * vb * idet;
        float ids = kf * va * idet;

        bool inb = (mx >= -50.f) && (mx <= (float)(WID + 50)) &&
                   (my >= -50.f) && (my <= (float)(HEI + 50));
        float op = inb ? opa[g] : 0.f;

        float lmax = 0.5f*(va + vd) + sqrtf(0.25f*(va - vd)*(va - vd) + vb*vb);
        float R2 = -1.0f;
        if (op > 0.01f) {
            float mthr = 2.0f * (__logf(op) + 4.6051701859880914f);  // 2 ln(100 op)
            R2 = lmax * mthr * 1.02f + 0.01f;
        }

        union { __half2 h2; float f; } urg, ubo;
        urg.h2 = __floats2half2_rn(col[g*3+0], col[g*3+1]);
        ubo.h2 = __floats2half2_rn(col[g*3+2], op);

        recA[g]   = make_float4(mx, my, ias, ibs);
        recB[g]   = make_float4(ids, Z, urg.f, ubo.f);
        cullR2[g] = R2;
    }
    __syncthreads();

    // ---- Phase A: cull vs this tile (one ballot per wave; gaussian id == tid) ----
    int bx = blockIdx.x & 15, by = blockIdx.x >> 4;
    float x0 = (float)(bx*8), x1 = x0 + 7.f;
    float y0 = (float)(by*8), y1 = y0 + 7.f;
    {
        float4 a = recA[tid];
        float R2 = cullR2[tid];
        float ddx = fmaxf(fmaxf(x0 - a.x, a.x - x1), 0.f);
        float ddy = fmaxf(fmaxf(y0 - a.y, a.y - y1), 0.f);
        bool keep = (ddx*ddx + ddy*ddy) < R2;
        unsigned long long m = __ballot(keep);
        if (ln == 0) { masks[wv] = m; counts[wv] = (int)__popcll(m); }
    }
    __syncthreads();

    // ---- Phase B: stable compaction (id order) + survivor depths ----
    int len = 0;
    #pragma unroll
    for (int j = 0; j < 16; ++j) len += counts[j];
    {
        int base = 0;
        #pragma unroll
        for (int j = 0; j < 16; ++j) base += (j < wv) ? counts[j] : 0;
        unsigned long long m = masks[wv];
        if ((m >> ln) & 1ull) {
            int p = base + (int)__popcll(m & ((1ull << ln) - 1ull));
            list[p] = tid;
            sdep[p] = recB[tid].y;
        }
    }
    if (tid < 4) sdep[len + tid] = -INFINITY;   // pad for float4 rank loop
    __syncthreads();

    // ---- Phase C: local stable rank by (depth desc, id asc), one i per thread ----
    if (tid < len) {
        int i = tid;
        float d = sdep[i];
        int rank = 0;
        const float4* sdep4 = (const float4*)sdep;
        int L4r = (len + 3) >> 2;
        for (int j4 = 0; j4 < L4r; ++j4) {
            float4 z = sdep4[j4];
            int jb = j4*4;
            rank += (z.x > d || (z.x == d && (jb+0) < i)) ? 1 : 0;
            rank += (z.y > d || (z.y == d && (jb+1) < i)) ? 1 : 0;
            rank += (z.z > d || (z.z == d && (jb+2) < i)) ? 1 : 0;
            rank += (z.w > d || (z.w == d && (jb+3) < i)) ? 1 : 0;
        }
        slist2[rank] = list[i];
    }
    __syncthreads();

    // ---- Phase D: composite, 16 chunk-lanes per pixel ----
    int p   = tid & 15;
    int pix = tid >> 4;
    int px  = bx*8 + (pix & 7);
    int py  = by*8 + (pix >> 3);
    float fpx = (float)px, fpy = (float)py;

    int L16 = (len + 15) >> 4;
    int s0 = p * L16;
    int s1 = min(len, s0 + L16);

    float T = 1.f, sr = 0.f, sg = 0.f, sb = 0.f, sd = 0.f, sa = 0.f;
    for (int i = s0; i < s1; ++i) {
        int id = slist2[i];
        float4 f0 = recA[id];
        float4 f1 = recB[id];

        float mx = f0.x, my = f0.y, ias = f0.z, ibs = f0.w;
        float ids = f1.x, dep = f1.y;
        union { float f; __half2 h2; } urg, ubo;
        urg.f = f1.z; ubo.f = f1.w;
        float cr = __low2float(urg.h2), cg = __high2float(urg.h2);
        float cb = __low2float(ubo.h2), op = __high2float(ubo.h2);

        float dx = fpx - mx, dy = fpy - my;
        float arg = ias*(dx*dx) + ibs*(dx*dy) + ids*(dy*dy);
        float w = exp2f(arg) * op;
        float al = (w > 0.01f) ? w : 0.f;
        float c = T * al;
        sr = fmaf(c, cr, sr);
        sg = fmaf(c, cg, sg);
        sb = fmaf(c, cb, sb);
        sd = fmaf(c, dep, sd);
        sa += c;
        T  -= c;
    }

    // Combine 16 chunk lanes: exclusive prefix-product of T, then sum.
    float v = T;
    #pragma unroll
    for (int d = 1; d < 16; d <<= 1) {
        float u = __shfl_up(v, d, 16);
        if (p >= d) v *= u;
    }
    float pre = __shfl_up(v, 1, 16);
    float P = (p == 0) ? 1.f : pre;

    sr *= P; sg *= P; sb *= P; sd *= P; sa *= P;
    #pragma unroll
    for (int m = 1; m < 16; m <<= 1) {
        sr += __shfl_xor(sr, m, 16);
        sg += __shfl_xor(sg, m, 16);
        sb += __shfl_xor(sb, m, 16);
        sd += __shfl_xor(sd, m, 16);
        sa += __shfl_xor(sa, m, 16);
    }

    if (p == 0) {
        int idx = py * WID + px;
        out[idx*3+0] = fminf(fmaxf(bg[0] + sr, 0.f), 1.f);
        out[idx*3+1] = fminf(fmaxf(bg[1] + sg, 0.f), 1.f);
        out[idx*3+2] = fminf(fmaxf(bg[2] + sb, 0.f), 1.f);
        out[HEI*WID*3 + idx] = sd;
        out[HEI*WID*4 + idx] = sa;
    }
}

extern "C" void kernel_launch(void* const* d_in, const int* in_sizes, int n_in,
                              void* d_out, int out_size, void* d_ws, size_t ws_size,
                              hipStream_t stream)
{
    const float* pos = (const float*)d_in[0];
    const float* scl = (const float*)d_in[1];
    const float* rot = (const float*)d_in[2];
    const float* col = (const float*)d_in[3];
    const float* opa = (const float*)d_in[4];
    const float* Km  = (const float*)d_in[5];
    const float* bg  = (const float*)d_in[6];
    float* out = (float*)d_out;

    hipLaunchKernelGGL(splat_k, dim3(256), dim3(1024), 0, stream,
                       pos, scl, rot, col, opa, Km, bg, out);
}

// Round 6
// 13.932 us; speedup vs baseline: 3.9087x; 1.0161x over previous
//
#include <hip/hip_runtime.h>
#include <hip/hip_fp16.h>
#include <math.h>

// Gaussian splat rasterizer, H=W=128, N=1024 — single fused kernel, 1024-thread blocks.
// One block per 8x8 tile (256 blocks). 16 waves/block = 4 waves/SIMD.
//  Phase 0+A: project gaussian tid (redundant per block) -> LDS records; immediately
//             cull vs this tile from registers (keep iff dist^2(mean, tile rect) < R2,
//             R2 = 1.02*lamMax*2ln(100 op); culled => alpha exactly 0, lossless) and
//             ballot the keep mask. One barrier.
//  Phase B: stable ballot+popc compaction in id order (depth from register).
//  Phase C: local stable rank by (depth desc, id asc) among survivors (one i/thread).
//  Phase D: 16 chunk-lanes per pixel; chunks combined by transmittance prefix-product
//           (1 - alpha_acc = prod(1 - alpha), exactly separable).
// Record A: mx, my, ias, ibs   Record B: ids, depth, half2(r,g), half2(b,op)
//   exponent arg = ias*dx^2 + ibs*dx*dy + ids*dy^2 (includes -0.5*log2e), w = exp2(arg)*op.

#define NG 1024
#define WID 128
#define HEI 128

__global__ __launch_bounds__(1024) void splat_k(
    const float* __restrict__ pos, const float* __restrict__ scl,
    const float* __restrict__ rot, const float* __restrict__ col,
    const float* __restrict__ opa, const float* __restrict__ Km,
    const float* __restrict__ bg, float* __restrict__ out)
{
    __shared__ __align__(16) float4 recA[NG];       // 16 KB
    __shared__ __align__(16) float4 recB[NG];       // 16 KB
    __shared__ __align__(16) float sdep[NG + 4];    // 4 KB + pad
    __shared__ int list[NG];                        // 4 KB
    __shared__ int slist2[NG];                      // 4 KB
    __shared__ unsigned long long masks[16];
    __shared__ int counts[16];

    int tid = threadIdx.x;
    int wv = tid >> 6, ln = tid & 63;
    int bx = blockIdx.x & 15, by = blockIdx.x >> 4;
    float x0 = (float)(bx*8), x1 = x0 + 7.f;
    float y0 = (float)(by*8), y1 = y0 + 7.f;
    float fx = Km[0], fy = Km[4], cx = Km[2], cy = Km[5];

    // ---- Phase 0+A: projection (one gaussian per thread) + immediate tile cull ----
    float Zdep;
    {
        int g = tid;
        float X = pos[g*3+0], Y = pos[g*3+1], Z = pos[g*3+2];
        float sx = scl[g*3+0], sy = scl[g*3+1], sz = scl[g*3+2];
        float4 q4 = ((const float4*)rot)[g];
        float qw = q4.x, qx = q4.y, qy = q4.z, qz = q4.w;

        float qn = 1.0f / sqrtf(qw*qw + qx*qx + qy*qy + qz*qz);
        qw *= qn; qx *= qn; qy *= qn; qz *= qn;

        float r00 = 1.f - 2.f*(qy*qy + qz*qz), r01 = 2.f*(qx*qy - qw*qz), r02 = 2.f*(qx*qz + qw*qy);
        float r10 = 2.f*(qx*qy + qw*qz), r11 = 1.f - 2.f*(qx*qx + qz*qz), r12 = 2.f*(qy*qz - qw*qx);
        float r20 = 2.f*(qx*qz - qw*qy), r21 = 2.f*(qy*qz + qw*qx), r22 = 1.f - 2.f*(qx*qx + qy*qy);

        float m00 = r00*sx, m01 = r01*sy, m02 = r02*sz;
        float m10 = r10*sx, m11 = r11*sy, m12 = r12*sz;
        float m20 = r20*sx, m21 = r21*sy, m22 = r22*sz;

        float c00 = m00*m00 + m01*m01 + m02*m02;
        float c01 = m00*m10 + m01*m11 + m02*m12;
        float c02 = m00*m20 + m01*m21 + m02*m22;
        float c11 = m10*m10 + m11*m11 + m12*m12;
        float c12 = m10*m20 + m11*m21 + m12*m22;
        float c22 = m20*m20 + m21*m21 + m22*m22;

        float zinv = 1.0f / (Z + 1e-6f);
        float mx = fx * X * zinv + cx;
        float my = fy * Y * zinv + cy;

        float j00 = fx * zinv,  j02 = -fx * X * zinv * zinv;
        float j11 = fy * zinv,  j12 = -fy * Y * zinv * zinv;

        float a0 = j00*c00 + j02*c02;
        float a1 = j00*c01 + j02*c12;
        float a2 = j00*c02 + j02*c22;
        float b1 = j11*c11 + j12*c12;
        float b2 = j11*c12 + j12*c22;

        float va = a0*j00 + a2*j02 + 1e-4f;
        float vb = a1*j11 + a2*j12;
        float vd = b1*j11 + b2*j12 + 1e-4f;

        float det  = va*vd - vb*vb;
        float idet = 1.0f / det;

        const float kf = -0.5f * 1.44269504088896340736f;  // -0.5*log2(e)
        float ias = kf * vd * idet;
        float ibs = -2.0f * kf * vb * idet;
        float ids = kf * va * idet;

        bool inb = (mx >= -50.f) && (mx <= (float)(WID + 50)) &&
                   (my >= -50.f) && (my <= (float)(HEI + 50));
        float op = inb ? opa[g] : 0.f;

        float lmax = 0.5f*(va + vd) + sqrtf(0.25f*(va - vd)*(va - vd) + vb*vb);
        float R2 = -1.0f;
        if (op > 0.01f) {
            float mthr = 2.0f * (__logf(op) + 4.6051701859880914f);  // 2 ln(100 op)
            R2 = lmax * mthr * 1.02f + 0.01f;
        }

        union { __half2 h2; float f; } urg, ubo;
        urg.h2 = __floats2half2_rn(col[g*3+0], col[g*3+1]);
        ubo.h2 = __floats2half2_rn(col[g*3+2], op);

        recA[g] = make_float4(mx, my, ias, ibs);
        recB[g] = make_float4(ids, Z, urg.f, ubo.f);
        Zdep = Z;

        // cull vs this tile, straight from registers
        float ddx = fmaxf(fmaxf(x0 - mx, mx - x1), 0.f);
        float ddy = fmaxf(fmaxf(y0 - my, my - y1), 0.f);
        bool keep = (ddx*ddx + ddy*ddy) < R2;
        unsigned long long m = __ballot(keep);
        if (ln == 0) { masks[wv] = m; counts[wv] = (int)__popcll(m); }
    }
    __syncthreads();

    // ---- Phase B: stable compaction (id order), depth from register ----
    int len = 0;
    #pragma unroll
    for (int j = 0; j < 16; ++j) len += counts[j];
    {
        int base = 0;
        #pragma unroll
        for (int j = 0; j < 16; ++j) base += (j < wv) ? counts[j] : 0;
        unsigned long long m = masks[wv];
        if ((m >> ln) & 1ull) {
            int p = base + (int)__popcll(m & ((1ull << ln) - 1ull));
            list[p] = tid;
            sdep[p] = Zdep;
        }
    }
    if (tid < 4) sdep[len + tid] = -INFINITY;   // pad for float4 rank loop
    __syncthreads();

    // ---- Phase C: local stable rank by (depth desc, id asc), one i per thread ----
    if (tid < len) {
        int i = tid;
        float d = sdep[i];
        int rank = 0;
        const float4* sdep4 = (const float4*)sdep;
        int L4r = (len + 3) >> 2;
        for (int j4 = 0; j4 < L4r; ++j4) {
            float4 z = sdep4[j4];
            int jb = j4*4;
            rank += (z.x > d || (z.x == d && (jb+0) < i)) ? 1 : 0;
            rank += (z.y > d || (z.y == d && (jb+1) < i)) ? 1 : 0;
            rank += (z.z > d || (z.z == d && (jb+2) < i)) ? 1 : 0;
            rank += (z.w > d || (z.w == d && (jb+3) < i)) ? 1 : 0;
        }
        slist2[rank] = list[i];
    }
    __syncthreads();

    // ---- Phase D: composite, 16 chunk-lanes per pixel ----
    int p   = tid & 15;
    int pix = tid >> 4;
    int px  = bx*8 + (pix & 7);
    int py  = by*8 + (pix >> 3);
    float fpx = (float)px, fpy = (float)py;

    int L16 = (len + 15) >> 4;
    int s0 = p * L16;
    int s1 = min(len, s0 + L16);

    float T = 1.f, sr = 0.f, sg = 0.f, sb = 0.f, sd = 0.f, sa = 0.f;
    for (int i = s0; i < s1; ++i) {
        int id = slist2[i];
        float4 f0 = recA[id];
        float4 f1 = recB[id];

        float mx = f0.x, my = f0.y, ias = f0.z, ibs = f0.w;
        float ids = f1.x, dep = f1.y;
        union { float f; __half2 h2; } urg, ubo;
        urg.f = f1.z; ubo.f = f1.w;
        float cr = __low2float(urg.h2), cg = __high2float(urg.h2);
        float cb = __low2float(ubo.h2), op = __high2float(ubo.h2);

        float dx = fpx - mx, dy = fpy - my;
        float arg = ias*(dx*dx) + ibs*(dx*dy) + ids*(dy*dy);
        float w = exp2f(arg) * op;
        float al = (w > 0.01f) ? w : 0.f;
        float c = T * al;
        sr = fmaf(c, cr, sr);
        sg = fmaf(c, cg, sg);
        sb = fmaf(c, cb, sb);
        sd = fmaf(c, dep, sd);
        sa += c;
        T  -= c;
    }

    // Combine 16 chunk lanes: exclusive prefix-product of T, then sum.
    float v = T;
    #pragma unroll
    for (int d = 1; d < 16; d <<= 1) {
        float u = __shfl_up(v, d, 16);
        if (p >= d) v *= u;
    }
    float pre = __shfl_up(v, 1, 16);
    float P = (p == 0) ? 1.f : pre;

    sr *= P; sg *= P; sb *= P; sd *= P; sa *= P;
    #pragma unroll
    for (int m = 1; m < 16; m <<= 1) {
        sr += __shfl_xor(sr, m, 16);
        sg += __shfl_xor(sg, m, 16);
        sb += __shfl_xor(sb, m, 16);
        sd += __shfl_xor(sd, m, 16);
        sa += __shfl_xor(sa, m, 16);
    }

    if (p == 0) {
        int idx = py * WID + px;
        out[idx*3+0] = fminf(fmaxf(bg[0] + sr, 0.f), 1.f);
        out[idx*3+1] = fminf(fmaxf(bg[1] + sg, 0.f), 1.f);
        out[idx*3+2] = fminf(fmaxf(bg[2] + sb, 0.f), 1.f);
        out[HEI*WID*3 + idx] = sd;
        out[HEI*WID*4 + idx] = sa;
    }
}

extern "C" void kernel_launch(void* const* d_in, const int* in_sizes, int n_in,
                              void* d_out, int out_size, void* d_ws, size_t ws_size,
                              hipStream_t stream)
{
    const float* pos = (const float*)d_in[0];
    const float* scl = (const float*)d_in[1];
    const float* rot = (const float*)d_in[2];
    const float* col = (const float*)d_in[3];
    const float* opa = (const float*)d_in[4];
    const float* Km  = (const float*)d_in[5];
    const float* bg  = (const float*)d_in[6];
    float* out = (float*)d_out;

    hipLaunchKernelGGL(splat_k, dim3(256), dim3(1024), 0, stream,
                       pos, scl, rot, col, opa, Km, bg, out);
}